// Round 3
// baseline (1019.237 us; speedup 1.0000x reference)
//
#include <hip/hip_runtime.h>
#include <stdint.h>

// HashedEmbeddingBag: out[b][d] = sum_{i<50} weight[(idx[b][i]*P1 + d*P2) % WS]
// WS = 2,000,000; B = 16384; L = 50; D = 128.
//
// R2: LDS-staged region sweep. R1 showed we're bound by the L1-miss/L2
// random-request path (104.9M line-granular gathers; VALU 6.5%, HBM 10%,
// time ~flat vs R0). Fix: gathers become ds_reads from an LDS-staged table
// region. Chain structure: 20*(P2 % WS) % WS = 4540, so for fixed (bag,i)
// the dims split into 20 chains d = r' + 20q with h stepping by 4540
// (chain span <= 27,240). Each block (1/CU, 64 bags) buckets its 64,000
// chains by base region (123 regions x 16K floats) into a private ws slab,
// then per region: stage 64KB tile (coalesced float4) -> visit buckets
// {r..r-3} (wrap-aware) -> analytic q-interval -> tile read + LDS atomicAdd
// into per-bag accumulators.

#define WS        2000000
#define EMB_DIM   128
#define BAG_LEN   50
#define BATCH     16384

#define NBLK      256
#define NTHR      512
#define BAGS_PB   (BATCH / NBLK)                 // 64
#define CHAINS_PB (BAGS_PB * BAG_LEN * 20)       // 64000
#define RSHIFT    14
#define RSIZE     (1 << RSHIFT)                  // 16384 floats = 64KB
#define NREG      ((WS + RSIZE - 1) / RSIZE)     // 123 (last region = 1152)
#define STEP      4540                           // (20*P2) % WS
#define SBIG      300227                         // P2 % WS

__global__ __launch_bounds__(NTHR) void heb_lds(
    const float* __restrict__ weight,
    const int*   __restrict__ indices,
    float*       __restrict__ out,
    uint32_t*    __restrict__ ws)
{
    __shared__ __align__(16) float tile[RSIZE];            // 64 KB
    __shared__ float    acc[BAGS_PB * EMB_DIM];            // 32 KB
    __shared__ uint32_t a_sm[BAGS_PB * BAG_LEN];           // 12.8 KB
    __shared__ uint32_t bstart[NREG + 1];
    __shared__ uint32_t bcur[NREG + 1];

    const int tid = threadIdx.x;
    const int bagBase = blockIdx.x * BAGS_PB;
    uint32_t* slab = ws + (size_t)blockIdx.x * CHAINS_PB;

    // ---- phase 1: zero acc + counters; hash index bases ----
    for (int j = tid; j < BAGS_PB * EMB_DIM; j += NTHR) acc[j] = 0.0f;
    for (int j = tid; j <= NREG; j += NTHR) bcur[j] = 0u;
    for (int j = tid; j < BAGS_PB * BAG_LEN; j += NTHR) {
        uint64_t idx = (uint64_t)(uint32_t)indices[bagBase * BAG_LEN + j];
        a_sm[j] = (uint32_t)((idx * 9824516537ull) % (uint64_t)WS);
    }
    __syncthreads();

    // ---- phase 2: count chains per base-region bucket ----
    for (int c = tid; c < CHAINS_PB; c += NTHR) {
        int bag = c / 1000;              // 50*20 chains per bag
        int rem = c - bag * 1000;
        int i   = rem / 20;
        int rp  = rem - i * 20;
        uint32_t A = (a_sm[bag * BAG_LEN + i] + (uint32_t)rp * (uint32_t)SBIG) % (uint32_t)WS;
        atomicAdd(&bcur[A >> RSHIFT], 1u);
    }
    __syncthreads();

    // ---- phase 3: serial prefix sum (124 entries; thread 0) ----
    if (tid == 0) {
        uint32_t run = 0;
        for (int b = 0; b < NREG; ++b) {
            uint32_t cnt = bcur[b];
            bstart[b] = run;
            bcur[b]   = run;             // becomes scatter cursor
            run += cnt;
        }
        bstart[NREG] = run;              // == CHAINS_PB
    }
    __syncthreads();

    // ---- phase 4: scatter packed chain entries into private ws slab ----
    // entry = A(21b) << 11 | bag(6b) << 5 | rp(5b)
    for (int c = tid; c < CHAINS_PB; c += NTHR) {
        int bag = c / 1000;
        int rem = c - bag * 1000;
        int i   = rem / 20;
        int rp  = rem - i * 20;
        uint32_t A = (a_sm[bag * BAG_LEN + i] + (uint32_t)rp * (uint32_t)SBIG) % (uint32_t)WS;
        uint32_t p = atomicAdd(&bcur[A >> RSHIFT], 1u);
        slab[p] = (A << 11) | ((uint32_t)bag << 5) | (uint32_t)rp;
    }
    // slab visibility for phase 5 is covered by the sync at region-loop top
    // (same-block threads; global writes then reads by same block).

    // ---- phase 5: region sweep ----
    for (int r = 0; r < NREG; ++r) {
        const int lo  = r << RSHIFT;
        const int len = min(RSIZE, WS - lo);
        __syncthreads();                         // protect tile (and slab, iter 0)

        // stage region into LDS (coalesced float4)
        for (int s = tid; s < (len >> 2); s += NTHR) {
            const float4 v = *(const float4*)(weight + lo + (s << 2));
            *(float4*)(tile + (s << 2)) = v;
        }
        __syncthreads();

        // visit buckets r, r-1, r-2 (+ r-3 only when the short bucket 122
        // can be inside the 27,240-element backward reach, i.e. r <= 2)
        const int nseg = (r >= 3) ? 3 : 4;
        for (int k = 0; k < nseg; ++k) {
            int b = r - k; if (b < 0) b += NREG;
            const int Aoff = (b > r) ? -WS : 0;  // wrapped segment
            const uint32_t e1 = bstart[b + 1];
            for (uint32_t j = bstart[b] + tid; j < e1; j += NTHR) {
                const uint32_t e = slab[j];
                const int A  = (int)(e >> 11);
                const int bg = (int)((e >> 5) & 63u);
                const int rp = (int)(e & 31u);
                const int base = A + Aoff - lo;      // pos(q) = base + q*STEP
                const int x = -base;                  // lo - Aeff
                const int y = x + len - 1;            // hi-1 - Aeff
                // ceil(x/4540), floor(y/4540) via non-negative offset 4*4540
                int q0 = (int)((uint32_t)(x + 18160 + 4539) / 4540u) - 4;
                int q1 = (int)((uint32_t)(y + 18160) / 4540u) - 4;
                if (q0 < 0) q0 = 0;
                const int qmax = (rp <= 7) ? 6 : 5;
                if (q1 > qmax) q1 = qmax;
                float* ap = acc + bg * EMB_DIM + rp;  // d = rp + 20q
                int pos = base + q0 * STEP;
                for (int q = q0; q <= q1; ++q) {
                    atomicAdd(ap + q * 20, tile[pos]);
                    pos += STEP;
                }
            }
        }
    }
    __syncthreads();

    // ---- phase 6: write out (coalesced) ----
    for (int j = tid; j < BAGS_PB * EMB_DIM; j += NTHR) {
        out[(size_t)bagBase * EMB_DIM + j] = acc[j];
    }
}

// ---- R1 fallback (if ws too small): direct predicated gather ----
#define NREG_FB   4
#define REG_FB    (WS / NREG_FB)

__global__ __launch_bounds__(128) void heb_gather_sum(
    const float* __restrict__ weight,
    const int*   __restrict__ indices,
    float*       __restrict__ out)
{
    __shared__ uint32_t a_sm[BAG_LEN];
    const int bag = blockIdx.x;
    const int d   = threadIdx.x;
    if (d < BAG_LEN) {
        uint64_t idx = (uint64_t)(uint32_t)indices[bag * BAG_LEN + d];
        a_sm[d] = (uint32_t)((idx * 9824516537ull) % (uint64_t)WS);
    }
    __syncthreads();
    const uint32_t c = ((uint32_t)d * 300227u) % (uint32_t)WS;
    float sum = 0.0f;
    for (uint32_t lo = 0; lo < (uint32_t)WS; lo += REG_FB) {
        const uint32_t hi = lo + REG_FB;
#pragma unroll
        for (int i = 0; i < BAG_LEN; ++i) {
            uint32_t h = a_sm[i] + c;
            if (h >= (uint32_t)WS) h -= (uint32_t)WS;
            if (h >= lo && h < hi) sum += weight[h];
        }
    }
    out[bag * EMB_DIM + d] = sum;
}

extern "C" void kernel_launch(void* const* d_in, const int* in_sizes, int n_in,
                              void* d_out, int out_size, void* d_ws, size_t ws_size,
                              hipStream_t stream)
{
    const float* weight  = (const float*)d_in[0];   // [2,000,000] fp32
    const int*   indices = (const int*)d_in[1];     // [16384*50] int
    float*       out     = (float*)d_out;           // [16384*128] fp32

    const size_t ws_needed = (size_t)NBLK * CHAINS_PB * sizeof(uint32_t); // 62.5 MB
    if (ws_size >= ws_needed) {
        heb_lds<<<NBLK, NTHR, 0, stream>>>(weight, indices, out, (uint32_t*)d_ws);
    } else {
        heb_gather_sum<<<BATCH, EMB_DIM, 0, stream>>>(weight, indices, out);
    }
}

// Round 4
// 841.834 us; speedup vs baseline: 1.2107x; 1.2107x over previous
//
#include <hip/hip_runtime.h>
#include <stdint.h>

// HashedEmbeddingBag: out[b][d] = sum_{i<50} weight[(idx[b][i]*P1 + d*P2) % WS]
// WS = 2,000,000; B = 16384; L = 50; D = 128.
//
// R3: LDS-staged region sweep, latency-hardened.
// R2 was latency-bound (8 waves/CU, dependent global slab loads per entry,
// 123 regions x barrier drains; VALU 8%, HBM 2%, nothing saturated).
// Changes: 1024-thread blocks (16 waves/CU); bucket entries staged into a
// rolling 3-slot LDS buffer so the gather loop is all-LDS; slab entries are
// u16 chain ids (A recomputed from a_sm -> slab 32MB, half traffic); tile
// staged via __builtin_amdgcn_global_load_lds width=16 (no VGPR roundtrip,
// no ds_write on the LDS pipe).
//
// Chain structure: 20*(P2%WS)%WS = 4540, so dims split into 20 chains
// d = rp + 20q, h = (Ac + q*4540) mod WS, Ac = (a + rp*300227) mod WS,
// span <= 27,240 < 2 regions -> each chain touches buckets b..b+2.

#define WS        2000000
#define EMB_DIM   128
#define BAG_LEN   50
#define BATCH     16384

#define NBLK      256
#define NTHR      1024
#define BAGS_PB   (BATCH / NBLK)                 // 64
#define CHAINS_PB (BAGS_PB * BAG_LEN * 20)       // 64000 (fits u16)
#define RSHIFT    14
#define RSIZE     (1 << RSHIFT)                  // 16384 floats = 64KB
#define NREG      ((WS + RSIZE - 1) / RSIZE)     // 123 (last region = 1152)
#define STEP      4540
#define SBIG      300227u                        // P2 % WS
#define BMAX      1024                           // bucket stage capacity

#define GLOAD_LDS16(gp, lp)                                            \
    __builtin_amdgcn_global_load_lds(                                  \
        (const __attribute__((address_space(1))) uint32_t*)(gp),       \
        (__attribute__((address_space(3))) uint32_t*)(lp), 16, 0, 0)

__device__ __forceinline__ void process_entry(
    uint32_t c, int Aoff, int lo, int len,
    const uint32_t* a_sm, const float* tile, float* acc)
{
    uint32_t bag = c / 1000u;
    uint32_t rem = c - bag * 1000u;
    uint32_t i   = rem / 20u;
    uint32_t rp  = rem - i * 20u;
    uint32_t Ac  = (a_sm[bag * BAG_LEN + i] + rp * SBIG) % (uint32_t)WS;
    const int base = (int)Ac + Aoff - lo;        // pos(q) = base + q*STEP
    const int x = -base;
    const int y = x + len - 1;
    // ceil(x/4540) and floor(y/4540) via non-negative unsigned division
    int q0 = (int)((uint32_t)(x + 22699) / 4540u) - 4;   // 4*4540 + 4539
    int q1 = (int)((uint32_t)(y + 18160) / 4540u) - 4;   // 4*4540
    if (q0 < 0) q0 = 0;
    const int nq = (rp <= 7u) ? 7 : 6;           // d = rp + 20q < 128
    if (q1 >= nq) q1 = nq - 1;
    float* ap = acc + bag * EMB_DIM + rp;
    int pos = base + q0 * STEP;
    for (int q = q0; q <= q1; ++q) {
        atomicAdd(ap + 20 * q, tile[pos]);       // ds_add_f32 (no return)
        pos += STEP;
    }
}

__global__ __launch_bounds__(NTHR) void heb_lds2(
    const float* __restrict__ weight,
    const int*   __restrict__ indices,
    float*       __restrict__ out,
    uint16_t*    __restrict__ ws)
{
    __shared__ __align__(16) float tile[RSIZE];            // 64 KB
    __shared__ float    acc[BAGS_PB * EMB_DIM];            // 32 KB
    __shared__ uint32_t a_sm[BAGS_PB * BAG_LEN];           // 12.8 KB
    __shared__ uint16_t ebuf[3][BMAX];                     // 6 KB
    __shared__ uint32_t bstart[NREG + 1];
    __shared__ uint32_t bcur[NREG];

    const int tid = threadIdx.x;
    const int bagBase = blockIdx.x * BAGS_PB;
    uint16_t* slab = ws + (size_t)blockIdx.x * CHAINS_PB;

    // ---- phase 1: zero acc + counters; hash index bases ----
    for (int j = tid; j < BAGS_PB * EMB_DIM; j += NTHR) acc[j] = 0.0f;
    for (int j = tid; j < NREG; j += NTHR) bcur[j] = 0u;
    for (int j = tid; j < BAGS_PB * BAG_LEN; j += NTHR) {
        uint64_t idx = (uint64_t)(uint32_t)indices[bagBase * BAG_LEN + j];
        a_sm[j] = (uint32_t)((idx * 9824516537ull) % (uint64_t)WS);
    }
    __syncthreads();

    // ---- phase 2: count chains per base-region bucket ----
    for (int c = tid; c < CHAINS_PB; c += NTHR) {
        uint32_t bag = (uint32_t)c / 1000u;
        uint32_t rem = (uint32_t)c - bag * 1000u;
        uint32_t i   = rem / 20u;
        uint32_t rp  = rem - i * 20u;
        uint32_t A = (a_sm[bag * BAG_LEN + i] + rp * SBIG) % (uint32_t)WS;
        atomicAdd(&bcur[A >> RSHIFT], 1u);
    }
    __syncthreads();

    // ---- phase 3: serial prefix sum (123 entries; thread 0) ----
    if (tid == 0) {
        uint32_t run = 0;
        for (int b = 0; b < NREG; ++b) {
            uint32_t cnt = bcur[b];
            bstart[b] = run;
            bcur[b]   = run;             // becomes scatter cursor
            run += cnt;
        }
        bstart[NREG] = run;              // == CHAINS_PB
    }
    __syncthreads();

    // ---- phase 4: scatter u16 chain ids into private ws slab ----
    for (int c = tid; c < CHAINS_PB; c += NTHR) {
        uint32_t bag = (uint32_t)c / 1000u;
        uint32_t rem = (uint32_t)c - bag * 1000u;
        uint32_t i   = rem / 20u;
        uint32_t rp  = rem - i * 20u;
        uint32_t A = (a_sm[bag * BAG_LEN + i] + rp * SBIG) % (uint32_t)WS;
        uint32_t p = atomicAdd(&bcur[A >> RSHIFT], 1u);
        slab[p] = (uint16_t)c;
    }
    // drained by the barrier at region-loop top (same-block write->read)

    // ---- phase 5: region sweep ----
    for (int r = 0; r < NREG; ++r) {
        const int lo  = r << RSHIFT;
        const int len = (RSIZE < WS - lo) ? RSIZE : (WS - lo);
        __syncthreads();                 // prior region done with tile/ebuf

        // stage region tile: async global->LDS, 16B per lane, contiguous
        for (int s = tid; s < (len >> 2); s += NTHR) {
            GLOAD_LDS16(weight + lo + (s << 2), &tile[s << 2]);
        }
        // stage bucket r entries into slot r%3 (contiguous coalesced run)
        {
            const uint32_t b0 = bstart[r];
            uint32_t cnt = bstart[r + 1] - b0;
            if (cnt > BMAX) cnt = BMAX;
            uint16_t* eb = ebuf[r % 3];
            for (uint32_t j = (uint32_t)tid; j < cnt; j += NTHR)
                eb[j] = slab[b0 + j];
        }
        __syncthreads();                 // vmcnt+lgkm drained by compiler

        // process staged buckets r, r-1, r-2 (all-LDS inner loop)
        for (int k = 0; k < 3; ++k) {
            const int b = r - k;
            if (b < 0) break;
            const uint32_t s0 = bstart[b], s1 = bstart[b + 1];
            uint32_t cnt = s1 - s0;
            const uint32_t sc = (cnt > BMAX) ? BMAX : cnt;
            const uint16_t* eb = ebuf[b % 3];
            for (uint32_t j = (uint32_t)tid; j < sc; j += NTHR)
                process_entry(eb[j], 0, lo, len, a_sm, tile, acc);
            // overflow tail (bucket > BMAX; probability ~0, correctness path)
            for (uint32_t j = s0 + BMAX + tid; j < s1; j += NTHR)
                process_entry(slab[j], 0, lo, len, a_sm, tile, acc);
        }
        // wrapped chains: buckets {120,121,122} reach region 0; {121,122} region 1
        if (r <= 1) {
            const int bw = (r == 0) ? 120 : 121;
            for (uint32_t j = bstart[bw] + tid; j < bstart[NREG]; j += NTHR)
                process_entry(slab[j], -WS, lo, len, a_sm, tile, acc);
        }
    }
    __syncthreads();

    // ---- phase 6: write out (coalesced) ----
    for (int j = tid; j < BAGS_PB * EMB_DIM; j += NTHR)
        out[(size_t)bagBase * EMB_DIM + j] = acc[j];
}

// ---- fallback (ws too small): R1 predicated direct gather ----
#define NREG_FB   4
#define REG_FB    (WS / NREG_FB)

__global__ __launch_bounds__(128) void heb_gather_sum(
    const float* __restrict__ weight,
    const int*   __restrict__ indices,
    float*       __restrict__ out)
{
    __shared__ uint32_t a_sm[BAG_LEN];
    const int bag = blockIdx.x;
    const int d   = threadIdx.x;
    if (d < BAG_LEN) {
        uint64_t idx = (uint64_t)(uint32_t)indices[bag * BAG_LEN + d];
        a_sm[d] = (uint32_t)((idx * 9824516537ull) % (uint64_t)WS);
    }
    __syncthreads();
    const uint32_t c = ((uint32_t)d * SBIG) % (uint32_t)WS;
    float sum = 0.0f;
    for (uint32_t lo = 0; lo < (uint32_t)WS; lo += REG_FB) {
        const uint32_t hi = lo + REG_FB;
#pragma unroll
        for (int i = 0; i < BAG_LEN; ++i) {
            uint32_t h = a_sm[i] + c;
            if (h >= (uint32_t)WS) h -= (uint32_t)WS;
            if (h >= lo && h < hi) sum += weight[h];
        }
    }
    out[bag * EMB_DIM + d] = sum;
}

extern "C" void kernel_launch(void* const* d_in, const int* in_sizes, int n_in,
                              void* d_out, int out_size, void* d_ws, size_t ws_size,
                              hipStream_t stream)
{
    const float* weight  = (const float*)d_in[0];   // [2,000,000] fp32
    const int*   indices = (const int*)d_in[1];     // [16384*50] int
    float*       out     = (float*)d_out;           // [16384*128] fp32

    const size_t ws_needed = (size_t)NBLK * CHAINS_PB * sizeof(uint16_t); // 32 MB
    if (ws_size >= ws_needed) {
        heb_lds2<<<NBLK, NTHR, 0, stream>>>(weight, indices, out, (uint16_t*)d_ws);
    } else {
        heb_gather_sum<<<BATCH, EMB_DIM, 0, stream>>>(weight, indices, out);
    }
}

// Round 5
// 414.631 us; speedup vs baseline: 2.4582x; 2.0303x over previous
//
#include <hip/hip_runtime.h>
#include <stdint.h>

// HashedEmbeddingBag: out[b][d] = sum_{i<50} weight[(idx[b][i]*P1 + d*P2) % WS]
// WS = 2,000,000; B = 16384; L = 50; D = 128.
//
// R4: sorted-stream register-accumulation sweep.
// R3 post-mortem: 3x chain-visit redundancy + q-loop max-over-lanes + LDS
// atomics + global slab latency inflated the instruction stream ~6x over
// useful work (VALU 17.5%, HBM 1.5%, nothing saturated). This version:
//  - sort each bag's 50 hash bases a_i = idx*P1 % WS once (rank-sort, LDS);
//  - thread (bag,d): its h_i = (a_i + c_d) mod WS in ascending order is just
//    a ROTATION of the sorted a-list (start = #{a < WS-c}); stream them;
//  - region sweep, double-buffered 64KB LDS tiles (global_load_lds 16B),
//    prefetch region r+1 while processing r; per region: while (h < hi)
//    sum += tile[h-lo], advance.  Register sums, no atomics, no workspace.
// 256 blocks x 1024 thr; 64 bags/block; thread handles 8 (bag,d) slots.

#define WS       2000000
#define EMB_DIM  128
#define BAG_LEN  50
#define BATCH    16384

#define NBLK     256
#define NTHR     1024
#define BAGS_PB  64
#define SLOTS    8                       // bags per thread
#define RSHIFT   14
#define RSIZE    (1 << RSHIFT)           // 16384 floats = 64KB
#define NREG     ((WS + RSIZE - 1) / RSIZE)   // 123 (last region = 1152)
#define SBIG     300227u                 // P2 % WS
#define APAD     52                      // padded bag stride

#define GLOAD_LDS16(gp, lp)                                            \
    __builtin_amdgcn_global_load_lds(                                  \
        (const __attribute__((address_space(1))) uint32_t*)(gp),       \
        (__attribute__((address_space(3))) uint32_t*)(lp), 16, 0, 0)

__global__ __launch_bounds__(NTHR, 4) void heb_sorted(
    const float* __restrict__ weight,
    const int*   __restrict__ indices,
    float*       __restrict__ out)
{
    __shared__ __align__(16) float tile[2][RSIZE];     // 128 KB
    __shared__ uint32_t a_sorted[BAGS_PB][APAD];       // 13.3 KB

    const int tid     = threadIdx.x;
    const int d       = tid & 127;
    const int bag_lo  = tid >> 7;          // wave-uniform
    const int bagBase = blockIdx.x * BAGS_PB;

    // scratch for unsorted hashes lives in tile[1] (dead until sweep r=0
    // prefetches region 1 into it, after the sort completes)
    uint32_t* araw = (uint32_t*)&tile[1][0];

    // ---- phase 1: load indices, hash base a = idx*P1 % WS ----
    for (int p = tid; p < BAGS_PB * BAG_LEN; p += NTHR) {
        uint32_t g = (uint32_t)p / 50u;
        uint32_t i = (uint32_t)p - g * 50u;
        uint64_t idx = (uint64_t)(uint32_t)indices[bagBase * BAG_LEN + p];
        araw[g * APAD + i] = (uint32_t)((idx * 9824516537ull) % (uint64_t)WS);
    }
    __syncthreads();

    // ---- phase 2: rank-sort each bag's 50 values (ties broken by index) ----
    for (int p = tid; p < BAGS_PB * BAG_LEN; p += NTHR) {
        uint32_t g = (uint32_t)p / 50u;
        uint32_t i = (uint32_t)p - g * 50u;
        uint32_t v = araw[g * APAD + i];
        int rank = 0;
        for (int q = 0; q < BAG_LEN; ++q) {
            uint32_t w = araw[g * APAD + q];
            rank += (w < v || (w == v && q < (int)i)) ? 1 : 0;
        }
        a_sorted[g][rank] = v;
    }
    __syncthreads();

    // ---- phase 3: stage region 0; init per-slot rotated stream state ----
    for (int s = tid; s < (RSIZE >> 2); s += NTHR)
        GLOAD_LDS16(weight + (s << 2), &tile[0][s << 2]);

    const uint32_t c   = ((uint32_t)d * SBIG) % (uint32_t)WS;
    const uint32_t wmc = (uint32_t)WS - c;     // in (0, WS]

    uint32_t pp[SLOTS], jj[SLOTS], hh[SLOTS];
    float    sm[SLOTS];
#pragma unroll
    for (int k = 0; k < SLOTS; ++k) {
        const int g = (bag_lo << 3) + k;
        int nlow = 0;
        for (int q = 0; q < BAG_LEN; ++q)
            nlow += (a_sorted[g][q] < wmc) ? 1 : 0;
        uint32_t s0 = (nlow >= BAG_LEN) ? 0u : (uint32_t)nlow;  // rotation start
        uint32_t t2 = a_sorted[g][s0] + c;
        uint32_t h0 = (t2 < t2 - (uint32_t)WS) ? t2 : t2 - (uint32_t)WS;
        pp[k] = s0; jj[k] = 0u; hh[k] = h0; sm[k] = 0.0f;
    }
    __syncthreads();   // barrier drains vmcnt -> region 0 resident

    // ---- phase 4: region sweep with double-buffered tiles ----
    for (int r = 0; r < NREG; ++r) {
        const int      lo = r << RSHIFT;
        const uint32_t hi = (uint32_t)lo + RSIZE;   // >WS on last region: fine
        const float*   tl = &tile[r & 1][0];

        // prefetch region r+1 into the other buffer (async, no wait here)
        if (r + 1 < NREG) {
            const int lo2  = (r + 1) << RSHIFT;
            const int len2 = (RSIZE < WS - lo2) ? RSIZE : (WS - lo2);
            float* nb = &tile[(r + 1) & 1][0];
            for (int s = tid; s < (len2 >> 2); s += NTHR)
                GLOAD_LDS16(weight + lo2 + (s << 2), nb + (s << 2));
        }

        // drain this region's entries from each slot's sorted stream
#pragma unroll
        for (int k = 0; k < SLOTS; ++k) {
            const int g = (bag_lo << 3) + k;
            const uint32_t* as = &a_sorted[g][0];
            uint32_t p_ = pp[k], j_ = jj[k], h_ = hh[k];
            float    s_ = sm[k];
            while (h_ < hi) {
                s_ += tl[h_ - (uint32_t)lo];
                p_ = (p_ + 1u == (uint32_t)BAG_LEN) ? 0u : p_ + 1u;
                ++j_;
                uint32_t t2 = as[p_] + c;
                uint32_t hn = (t2 < t2 - (uint32_t)WS) ? t2 : t2 - (uint32_t)WS;
                h_ = (j_ < (uint32_t)BAG_LEN) ? hn : 0xFFFFFFFFu;
            }
            pp[k] = p_; jj[k] = j_; hh[k] = h_; sm[k] = s_;
        }
        __syncthreads();   // next buffer staged + everyone done with tl
    }

    // ---- phase 5: coalesced output ----
#pragma unroll
    for (int k = 0; k < SLOTS; ++k) {
        const int g = (bag_lo << 3) + k;
        out[(size_t)(bagBase + g) * EMB_DIM + d] = sm[k];
    }
}

extern "C" void kernel_launch(void* const* d_in, const int* in_sizes, int n_in,
                              void* d_out, int out_size, void* d_ws, size_t ws_size,
                              hipStream_t stream)
{
    const float* weight  = (const float*)d_in[0];   // [2,000,000] fp32
    const int*   indices = (const int*)d_in[1];     // [16384*50] int
    float*       out     = (float*)d_out;           // [16384*128] fp32

    heb_sorted<<<NBLK, NTHR, 0, stream>>>(weight, indices, out);
}

// Round 6
// 351.037 us; speedup vs baseline: 2.9035x; 1.1812x over previous
//
#include <hip/hip_runtime.h>
#include <stdint.h>

// HashedEmbeddingBag: out[b][d] = sum_{i<50} weight[(idx[b][i]*P1 + d*P2) % WS]
// WS = 2,000,000; B = 16384; L = 50; D = 128.
//
// R5: extended-sorted-array stream (R4 minus all wrap/counter logic).
// R4 was VALU-issue bound (65% busy): ~13 VALU + 2 ds_read per stream step
// (rotation wrap cndmasks, j-counter select, unscaled addressing). Fix via
// identity: with s0 = #{a < WS-c}, the ascending h-stream of thread (bag,d)
// is h = ext[t] + (c - WS), t = s0..s0+49, where ext = [sorted_a | sorted_a
// + WS | sentinels]. Monotone + sentinel => self-terminating; store ext
// pre-scaled x4 so the loop is: addr-add, ds_read tile, f32-add, t+=4,
// ds_read ext, h-add, cmp  (~6 VALU + 2 DS). Last-region hi clamped to 4*WS
// so post-stream values (>= 4*(h+WS) >= 8e6) never re-enter.
// Double-buffered 64KB tiles (global_load_lds 16B), register sums, no ws.

#define WS       2000000
#define EMB_DIM  128
#define BAG_LEN  50
#define BATCH    16384

#define NBLK     256
#define NTHR     1024
#define BAGS_PB  64
#define SLOTS    8                       // bags per thread
#define RSHIFT   14
#define RSIZE    (1 << RSHIFT)           // 16384 floats = 64KB
#define NREG     ((WS + RSIZE - 1) / RSIZE)   // 123 (last region = 1152)
#define SBIG     300227u                 // P2 % WS
#define EXT_N    104                     // 50 + 50 + 4 sentinels
#define SENT4    0x10000000u             // sentinel (scaled domain), >> 4*WS

#define GLOAD_LDS16(gp, lp)                                            \
    __builtin_amdgcn_global_load_lds(                                  \
        (const __attribute__((address_space(1))) uint32_t*)(gp),       \
        (__attribute__((address_space(3))) uint32_t*)(lp), 16, 0, 0)

__global__ __launch_bounds__(NTHR, 4) void heb_ext(
    const float* __restrict__ weight,
    const int*   __restrict__ indices,
    float*       __restrict__ out)
{
    __shared__ __align__(16) float tile[2][RSIZE];     // 128 KB
    __shared__ uint32_t ext4[BAGS_PB][EXT_N];          // 26.6 KB

    const int tid     = threadIdx.x;
    const int d       = tid & 127;
    const int bag_lo  = tid >> 7;          // wave-uniform
    const int bagBase = blockIdx.x * BAGS_PB;

    // scratch for unsorted hashes in tile[1] (dead until the r=0 iteration
    // prefetches region 1 into it, which happens after the sort barrier)
    uint32_t* araw = (uint32_t*)&tile[1][0];

    // ---- phase 1: load indices, hash base a = idx*P1 % WS ----
    for (int p = tid; p < BAGS_PB * BAG_LEN; p += NTHR) {
        uint32_t g = (uint32_t)p / 50u;
        uint32_t i = (uint32_t)p - g * 50u;
        uint64_t idx = (uint64_t)(uint32_t)indices[bagBase * BAG_LEN + p];
        araw[g * 52 + i] = (uint32_t)((idx * 9824516537ull) % (uint64_t)WS);
    }
    __syncthreads();

    // ---- phase 2: rank-sort each bag (ties by index); build ext4 ----
    for (int p = tid; p < BAGS_PB * BAG_LEN; p += NTHR) {
        uint32_t g = (uint32_t)p / 50u;
        uint32_t i = (uint32_t)p - g * 50u;
        uint32_t v = araw[g * 52 + i];
        int rank = 0;
        for (int q = 0; q < BAG_LEN; ++q) {
            uint32_t w = araw[g * 52 + q];
            rank += (w < v || (w == v && q < (int)i)) ? 1 : 0;
        }
        ext4[g][rank]      = v << 2;                 // 4*a
        ext4[g][rank + 50] = (v + (uint32_t)WS) << 2; // 4*(a+WS)
    }
    for (int p = tid; p < BAGS_PB * 4; p += NTHR)
        ext4[p >> 2][100 + (p & 3)] = SENT4;
    __syncthreads();

    // ---- phase 3: stage region 0 (async); init per-slot streams ----
    for (int s = tid; s < (RSIZE >> 2); s += NTHR)
        GLOAD_LDS16(weight + (s << 2), &tile[0][s << 2]);

    const uint32_t c    = ((uint32_t)d * SBIG) % (uint32_t)WS;
    const uint32_t C4   = (uint32_t)(((int)c - WS) * 4);  // 4*(c-WS) mod 2^32
    const uint32_t wmc4 = ((uint32_t)WS - c) << 2;

    uint32_t t4[SLOTS], h4[SLOTS];
    float    sm[SLOTS];
#pragma unroll
    for (int k = 0; k < SLOTS; ++k) {
        const uint32_t* eg = &ext4[(bag_lo << 3) + k][0];
        int nlow = 0;
        for (int q = 0; q < BAG_LEN; ++q)      // broadcast reads (free)
            nlow += (eg[q] < wmc4) ? 1 : 0;
        t4[k] = (uint32_t)nlow << 2;           // byte offset into ext4[g]
        h4[k] = eg[nlow] + C4;                 // 4*h of first stream entry
        sm[k] = 0.0f;
    }
    __syncthreads();   // barrier drains vmcnt -> region 0 resident

    // ---- phase 4: region sweep, double-buffered ----
    for (int r = 0; r < NREG; ++r) {
        const uint32_t lo4 = ((uint32_t)(r << RSHIFT)) << 2;
        const uint32_t hi4 = (r == NREG - 1) ? (uint32_t)(4 * WS)
                                             : lo4 + ((uint32_t)RSIZE << 2);
        const char* tb = (const char*)&tile[r & 1][0];

        // prefetch region r+1 into the other buffer (async; drained by the
        // end-of-region barrier, so it overlaps this region's processing)
        if (r + 1 < NREG) {
            const int lo2  = (r + 1) << RSHIFT;
            const int len2 = (RSIZE < WS - lo2) ? RSIZE : (WS - lo2);
            float* nb = &tile[(r + 1) & 1][0];
            for (int s = tid; s < (len2 >> 2); s += NTHR)
                GLOAD_LDS16(weight + lo2 + (s << 2), nb + (s << 2));
        }

        // drain each slot's stream for this region (lean all-LDS loop)
#pragma unroll
        for (int k = 0; k < SLOTS; ++k) {
            const char* eg = (const char*)&ext4[(bag_lo << 3) + k][0];
            uint32_t t_ = t4[k], h_ = h4[k];
            float    s_ = sm[k];
            while (h_ < hi4) {
                s_ += *(const float*)(tb + (h_ - lo4));
                t_ += 4u;
                h_ = *(const uint32_t*)(eg + t_) + C4;
            }
            t4[k] = t_; h4[k] = h_; sm[k] = s_;
        }
        __syncthreads();   // everyone done with tb + next buffer staged
    }

    // ---- phase 5: coalesced output ----
#pragma unroll
    for (int k = 0; k < SLOTS; ++k) {
        const int g = (bag_lo << 3) + k;
        out[(size_t)(bagBase + g) * EMB_DIM + d] = sm[k];
    }
}

extern "C" void kernel_launch(void* const* d_in, const int* in_sizes, int n_in,
                              void* d_out, int out_size, void* d_ws, size_t ws_size,
                              hipStream_t stream)
{
    const float* weight  = (const float*)d_in[0];   // [2,000,000] fp32
    const int*   indices = (const int*)d_in[1];     // [16384*50] int
    float*       out     = (float*)d_out;           // [16384*128] fp32

    heb_ext<<<NBLK, NTHR, 0, stream>>>(weight, indices, out);
}

// Round 8
// 272.348 us; speedup vs baseline: 3.7424x; 1.2889x over previous
//
#include <hip/hip_runtime.h>
#include <stdint.h>

// HashedEmbeddingBag: out[b][d] = sum_{i<50} weight[(idx[b][i]*P1 + d*P2) % WS]
// WS = 2,000,000; B = 16384; L = 50; D = 128.
//
// R7: R5's proven sorted-stream skeleton (per-bag ext arrays, register
// sums, no atomics — R6's merged-stream variant was nondeterministic on
// replay and is abandoned) with a SINGLE 128KB tile instead of 2x64KB
// double buffer. Cost model (validated on R5): LDS-pipe cycles ~ regions x
// E[max-over-64-lanes Poisson(lambda)], lambda = 50*RSIZE/WS. RSIZE 16384
// -> 32768 halves region count (123 -> 62) while max-over-lanes grows only
// 2.6 -> 3.6; staging is now exposed (~60us of L2 fetch) but the while-loop
// LDS work drops ~1.5x. Inner loop is R5 verbatim: with s0 = #{a < WS-c},
// the ascending h-stream of thread (bag,d) is h = ext[t] + (c-WS),
// t = s0..s0+49, ext = [4*sorted_a | 4*(sorted_a+WS) | sentinels];
// monotone + sentinels => self-terminating per region.

#define WS       2000000
#define EMB_DIM  128
#define BAG_LEN  50
#define BATCH    16384

#define NBLK     256
#define NTHR     1024
#define BAGS_PB  64
#define SLOTS    8                       // bags per thread
#define RSIZE    32768                   // floats per region tile (128KB)
#define NREG     62                      // 61 full + last region 1152
#define SBIG     300227u                 // P2 % WS
#define EXT_N    104                     // 50 + 50 + 4 sentinels
#define SENT4    0x10000000u             // scaled-domain sentinel >> 4*WS

#define GLOAD_LDS16(gp, lp)                                            \
    __builtin_amdgcn_global_load_lds(                                  \
        (const __attribute__((address_space(1))) uint32_t*)(gp),       \
        (__attribute__((address_space(3))) uint32_t*)(lp), 16, 0, 0)

__global__ __launch_bounds__(NTHR, 4) void heb_single(
    const float* __restrict__ weight,
    const int*   __restrict__ indices,
    float*       __restrict__ out)
{
    __shared__ __align__(16) float tile[RSIZE];        // 128 KB
    __shared__ uint32_t ext4[BAGS_PB][EXT_N];          // 26.6 KB

    const int tid     = threadIdx.x;
    const int d       = tid & 127;
    const int bag_lo  = tid >> 7;          // wave-uniform
    const int bagBase = blockIdx.x * BAGS_PB;

    // unsorted-hash scratch lives in tile (dead before first staging,
    // which happens after the phase-2 barrier + loop-top barrier)
    uint32_t* araw = (uint32_t*)&tile[0];  // [64][52]

    // ---- phase 1: load indices, hash base a = idx*P1 % WS ----
    for (int p = tid; p < BAGS_PB * BAG_LEN; p += NTHR) {
        uint32_t g = (uint32_t)p / 50u;
        uint32_t i = (uint32_t)p - g * 50u;
        uint64_t idx = (uint64_t)(uint32_t)indices[bagBase * BAG_LEN + p];
        araw[g * 52 + i] = (uint32_t)((idx * 9824516537ull) % (uint64_t)WS);
    }
    __syncthreads();

    // ---- phase 2: rank-sort each bag (ties by index); build ext4 ----
    for (int p = tid; p < BAGS_PB * BAG_LEN; p += NTHR) {
        uint32_t g = (uint32_t)p / 50u;
        uint32_t i = (uint32_t)p - g * 50u;
        uint32_t v = araw[g * 52 + i];
        int rank = 0;
        for (int q = 0; q < BAG_LEN; ++q) {
            uint32_t w = araw[g * 52 + q];
            rank += (w < v || (w == v && q < (int)i)) ? 1 : 0;
        }
        ext4[g][rank]      = v << 2;                  // 4*a
        ext4[g][rank + 50] = (v + (uint32_t)WS) << 2; // 4*(a+WS)
    }
    for (int p = tid; p < BAGS_PB * 4; p += NTHR)
        ext4[p >> 2][100 + (p & 3)] = SENT4;
    __syncthreads();                       // araw dead from here on

    // ---- phase 3: init per-slot rotated stream state (reads ext4) ----
    const uint32_t c    = ((uint32_t)d * SBIG) % (uint32_t)WS;
    const uint32_t C4   = (uint32_t)(((int)c - WS) * 4);  // 4*(c-WS) mod 2^32
    const uint32_t wmc4 = ((uint32_t)WS - c) << 2;

    uint32_t t4[SLOTS], h4[SLOTS];
    float    sm[SLOTS];
#pragma unroll
    for (int k = 0; k < SLOTS; ++k) {
        const uint32_t* eg = &ext4[(bag_lo << 3) + k][0];
        int nlow = 0;
        for (int q = 0; q < BAG_LEN; ++q)      // broadcast reads (free)
            nlow += (eg[q] < wmc4) ? 1 : 0;
        t4[k] = (uint32_t)nlow << 2;           // byte offset into ext4[g]
        h4[k] = eg[nlow] + C4;                 // 4*h of first stream entry
        sm[k] = 0.0f;
    }

    // ---- phase 4: region sweep, single buffer (stage -> drain -> process) ----
    for (int r = 0; r < NREG; ++r) {
        const int lo  = r * RSIZE;
        const int len = (RSIZE < WS - lo) ? RSIZE : (WS - lo);
        __syncthreads();                 // all threads done with prev tile
                                         // (and phases 1-3 at r=0)

        for (int s = tid; s < (len >> 2); s += NTHR)
            GLOAD_LDS16(weight + lo + (s << 2), &tile[s << 2]);
        __syncthreads();                 // barrier drains vmcnt -> tile valid

        const uint32_t lo4 = ((uint32_t)lo) << 2;
        const uint32_t hi4 = (r == NREG - 1) ? (uint32_t)(4 * WS)
                                             : lo4 + ((uint32_t)RSIZE << 2);
        const char* tb = (const char*)&tile[0];

#pragma unroll
        for (int k = 0; k < SLOTS; ++k) {
            const char* eg = (const char*)&ext4[(bag_lo << 3) + k][0];
            uint32_t t_ = t4[k], h_ = h4[k];
            float    s_ = sm[k];
            while (h_ < hi4) {
                s_ += *(const float*)(tb + (h_ - lo4));
                t_ += 4u;
                h_ = *(const uint32_t*)(eg + t_) + C4;
            }
            t4[k] = t_; h4[k] = h_; sm[k] = s_;
        }
    }

    // ---- phase 5: coalesced output ----
#pragma unroll
    for (int k = 0; k < SLOTS; ++k) {
        const int g = (bag_lo << 3) + k;
        out[(size_t)(bagBase + g) * EMB_DIM + d] = sm[k];
    }
}

extern "C" void kernel_launch(void* const* d_in, const int* in_sizes, int n_in,
                              void* d_out, int out_size, void* d_ws, size_t ws_size,
                              hipStream_t stream)
{
    const float* weight  = (const float*)d_in[0];   // [2,000,000] fp32
    const int*   indices = (const int*)d_in[1];     // [16384*50] int
    float*       out     = (float*)d_out;           // [16384*128] fp32

    heb_single<<<NBLK, NTHR, 0, stream>>>(weight, indices, out);
}